// Round 14
// baseline (406.062 us; speedup 1.0000x reference)
//
#include <hip/hip_runtime.h>
#include <hip/hip_bf16.h>

// out[n,d] = b[d] + pk[n,d] + max_m ok[n,m,d]
//   pk = p @ Wp^T  (2048x1024,  K=1024)   -- small 128-tile kernel
//   ok = o @ Wo^T  (65536x1024, K=1024)   -- fused-convert 128^2 GEMM
// R14 = R13 + B double-buffer (staged one tile ahead):
//   every vmcnt wait now targets loads issued a FULL tile earlier ->
//   zero exposed VMEM latency in the loop. LDS 48KB (A 16K + B 2x16K),
//   still 3 blocks/CU. Single VMCNT(0) per tile (all loads >=1 tile old).

#define NN 2048
#define MM 32
#define CC 1024

typedef __attribute__((ext_vector_type(8))) __bf16 bf16x8;
typedef __attribute__((ext_vector_type(4))) float f32x4;
typedef __attribute__((ext_vector_type(8))) unsigned short u16x8;
typedef __attribute__((ext_vector_type(4))) unsigned short u16x4;

__device__ inline unsigned short f2bf(float f) {
  union { __hip_bfloat16 h; unsigned short u; } v;
  v.h = __float2bfloat16(f);
  return v.u;
}

__device__ inline void gload_lds16(const void* g, void* l) {
  __builtin_amdgcn_global_load_lds(
      (const __attribute__((address_space(1))) void*)g,
      (__attribute__((address_space(3))) void*)l, 16, 0, 0);
}

// ---- convert person_features + split W into Wp/Wo (bf16) ----
__global__ void conv_pw(const float* __restrict__ p, const float* __restrict__ W,
                        unsigned short* __restrict__ pd,
                        unsigned short* __restrict__ wp,
                        unsigned short* __restrict__ wo) {
  const int PG = (NN * CC) / 8;
  const int WG = (CC * 2 * CC) / 8;
  int i = blockIdx.x * blockDim.x + threadIdx.x;
  int stride = gridDim.x * blockDim.x;
  for (; i < PG + WG; i += stride) {
    if (i < PG) {
      const float4* s = reinterpret_cast<const float4*>(p) + (size_t)i * 2;
      float4 a = s[0], b = s[1];
      u16x8 r;
      r[0] = f2bf(a.x); r[1] = f2bf(a.y); r[2] = f2bf(a.z); r[3] = f2bf(a.w);
      r[4] = f2bf(b.x); r[5] = f2bf(b.y); r[6] = f2bf(b.z); r[7] = f2bf(b.w);
      *reinterpret_cast<u16x8*>(pd + (size_t)i * 8) = r;
    } else {
      int f = i - PG;
      int e = f * 8;
      int d = e >> 11;
      int cc = e & 2047;
      const float4* s = reinterpret_cast<const float4*>(W) + (size_t)f * 2;
      float4 a = s[0], b = s[1];
      u16x8 r;
      r[0] = f2bf(a.x); r[1] = f2bf(a.y); r[2] = f2bf(a.z); r[3] = f2bf(a.w);
      r[4] = f2bf(b.x); r[5] = f2bf(b.y); r[6] = f2bf(b.z); r[7] = f2bf(b.w);
      unsigned short* o = (cc < CC) ? (wp + (size_t)d * CC + cc)
                                    : (wo + (size_t)d * CC + (cc - CC));
      *reinterpret_cast<u16x8*>(o) = r;
    }
  }
}

// ---- small 128x128 GEMM for pk+b ----
__global__ void gemm_pk(const unsigned short* __restrict__ A,
                        const unsigned short* __restrict__ B,
                        const float* __restrict__ bvec,
                        float* __restrict__ out) {
  __shared__ unsigned short As[128 * 64];
  __shared__ unsigned short Bs[128 * 64];

  int nb = gridDim.x;
  int chunk = nb >> 3;
  int obid = blockIdx.x;
  int vb = (obid & 7) * chunk + (obid >> 3);
  int bcol = vb & 7;
  int brow = vb >> 3;

  int tid = threadIdx.x;
  int l = tid & 63;
  int wid = tid >> 6;
  int wr = wid >> 1, wc = wid & 1;
  int lr = l & 15;
  int lk = (l >> 4) << 3;

  const unsigned short* gA = A + (size_t)brow * 128 * CC;
  const unsigned short* gB = B + (size_t)bcol * 128 * CC;

  f32x4 acc[4][4] = {};

  for (int kt = 0; kt < 16; ++kt) {
    int k0 = kt * 64;
#pragma unroll
    for (int j = 0; j < 4; ++j) {
      int f = (j * 256 + tid) * 8;
      int r = f >> 6;
      int c = f & 63;
      gload_lds16(gA + (size_t)r * CC + k0 + c, &As[f]);
      gload_lds16(gB + (size_t)r * CC + k0 + c, &Bs[f]);
    }
    __syncthreads();
#pragma unroll
    for (int kk = 0; kk < 2; ++kk) {
      bf16x8 af[4], bfr[4];
#pragma unroll
      for (int mi = 0; mi < 4; ++mi)
        af[mi] = *reinterpret_cast<const bf16x8*>(
            &As[(wr * 64 + mi * 16 + lr) * 64 + kk * 32 + lk]);
#pragma unroll
      for (int ni = 0; ni < 4; ++ni)
        bfr[ni] = *reinterpret_cast<const bf16x8*>(
            &Bs[(wc * 64 + ni * 16 + lr) * 64 + kk * 32 + lk]);
#pragma unroll
      for (int mi = 0; mi < 4; ++mi)
#pragma unroll
        for (int ni = 0; ni < 4; ++ni)
          acc[mi][ni] = __builtin_amdgcn_mfma_f32_16x16x32_bf16(
              af[mi], bfr[ni], acc[mi][ni], 0, 0, 0);
    }
    __syncthreads();
  }

#pragma unroll
  for (int mi = 0; mi < 4; ++mi) {
    int row = brow * 128 + wr * 64 + mi * 16 + (l >> 4) * 4;
#pragma unroll
    for (int ni = 0; ni < 4; ++ni) {
      int col = bcol * 128 + wc * 64 + ni * 16 + lr;
      float bb = bvec[col];
#pragma unroll
      for (int r = 0; r < 4; ++r)
        out[(size_t)(row + r) * CC + col] = acc[mi][ni][r] + bb;
    }
  }
}

// ==================== 128x128 fused GEMM, B-dbuf (R14) ======================
// LDS: A [128 x 64 bf16, 128B rows] @ 0 (16KB); Bbuf0 @ 16384; Bbuf1 @ 32768.
// Swizzle: LDS cell (row, chunk16B c) holds logical chunk c ^ (row&7).

#define BARRIER                                      \
  do {                                               \
    asm volatile("" ::: "memory");                   \
    __builtin_amdgcn_s_barrier();                    \
    asm volatile("" ::: "memory");                   \
  } while (0)

#define LGKM0 asm volatile("s_waitcnt lgkmcnt(0)" ::: "memory")
#define VMCNT(n) asm volatile("s_waitcnt vmcnt(" #n ")" ::: "memory")

// B stage into buf bs: 128x64 bf16 = 16KB; 4 x gload_lds16/thread.
#define STAGE_B(bs, k0)                                                       \
  do {                                                                        \
    _Pragma("unroll") for (int j = 0; j < 4; ++j)                             \
        gload_lds16(gB + (size_t)(j * 32 + brr) * CC + (k0) + bsc,            \
                    lds + 16384 + (bs) * 16384 + (j * 256 + tid) * 16);       \
  } while (0)

// A issue: instr j -> rows j*16 + (tid>>4), 16B col tid&15 (coalesced).
#define ISSUE_A(k0)                                                           \
  do {                                                                        \
    _Pragma("unroll") for (int j = 0; j < 8; ++j)                             \
        aL[j] = *reinterpret_cast<const float4*>(                             \
            gAf + (size_t)(j * 16 + arow0) * CC + (k0) + ac4 * 4);            \
  } while (0)

// cvt + swizzled ds_write_b64 into the A region
#define CVT_WRITE_A                                                           \
  do {                                                                        \
    _Pragma("unroll") for (int j = 0; j < 8; ++j) {                           \
      u16x4 r;                                                                \
      r[0] = f2bf(aL[j].x); r[1] = f2bf(aL[j].y);                             \
      r[2] = f2bf(aL[j].z); r[3] = f2bf(aL[j].w);                             \
      *reinterpret_cast<u16x4*>(lds + (j * 16 + arow0) * 128 + aswz) = r;     \
    }                                                                         \
  } while (0)

#define MFMA16X                                                               \
  do {                                                                        \
    __builtin_amdgcn_s_setprio(1);                                            \
    _Pragma("unroll") for (int mi = 0; mi < 4; ++mi)                          \
        _Pragma("unroll") for (int ni = 0; ni < 4; ++ni)                      \
            acc[mi][ni] = __builtin_amdgcn_mfma_f32_16x16x32_bf16(            \
                af[mi], bfr[ni], acc[mi][ni], 0, 0, 0);                       \
    __builtin_amdgcn_s_setprio(0);                                            \
  } while (0)

// One K-tile t; B read from buf bs, B(t+1) staged into buf nbs.
// Entering: outstanding = [B(t):4, A(t):8], ALL issued at tile t-1.
#define TILE(t, bs, nbs)                                                      \
  do {                                                                        \
    BARRIER;                 /* tile t-1 LDS reads done (A + Bbuf nbs) */     \
    VMCNT(0);                /* retire A(t)+B(t): all >=1 tile old */         \
    CVT_WRITE_A;             /* A(t) f32 regs -> bf16 LDS (swizzled) */       \
    if ((t) + 1 < 16) {                                                       \
      STAGE_B(nbs, ((t) + 1) * 64);   /* B(t+1) DMA [4] */                    \
      ISSUE_A(((t) + 1) * 64);        /* A(t+1) [8]     */                    \
    }                                                                         \
    LGKM0;                   /* our ds_writes visible */                      \
    BARRIER;                 /* LDS tile t ready for all waves */             \
    _Pragma("unroll") for (int mi = 0; mi < 4; ++mi)                          \
        af[mi] = *(const bf16x8*)(lds + a_k0 + mi * 2048);                    \
    _Pragma("unroll") for (int ni = 0; ni < 4; ++ni)                          \
        bfr[ni] = *(const bf16x8*)(lds + 16384 + (bs) * 16384 + b_k0 +        \
                                   ni * 2048);                                \
    LGKM0;                                                                    \
    MFMA16X;                                                                  \
    _Pragma("unroll") for (int mi = 0; mi < 4; ++mi)                          \
        af[mi] = *(const bf16x8*)(lds + a_k1 + mi * 2048);                    \
    _Pragma("unroll") for (int ni = 0; ni < 4; ++ni)                          \
        bfr[ni] = *(const bf16x8*)(lds + 16384 + (bs) * 16384 + b_k1 +        \
                                   ni * 2048);                                \
    LGKM0;                                                                    \
    MFMA16X;                                                                  \
  } while (0)

__global__ __launch_bounds__(256, 3) void gemm_fused(
    const float* __restrict__ A,
    const unsigned short* __restrict__ B,
    const float* __restrict__ pkb,
    float* __restrict__ out) {
  __shared__ char lds[49152];

  int obid = blockIdx.x;                    // 4096 blocks
  int vb = (obid & 7) * 512 + (obid >> 3);  // XCD-contiguous (4096 % 8 == 0)
  int bcol = vb & 7;                        // 8 col tiles (col-fastest: L2 A-reuse)
  int brow = vb >> 3;                       // 512 row tiles

  int tid = threadIdx.x;
  int l = tid & 63;
  int wid = tid >> 6;
  int wr = wid >> 1;   // 0..1 (M half)
  int wc = wid & 1;    // 0..1 (N half)
  int lr = l & 15;
  int g = l >> 4;      // 0..3

  const float* gAf = A + (size_t)brow * 128 * CC;
  const unsigned short* gB = B + (size_t)bcol * 128 * CC;

  // B staging addressing (linear LDS dest, inverse-swizzled global source)
  int brr = tid >> 3;                            // 0..31
  int bsc = ((tid & 7) ^ ((tid >> 3) & 7)) * 8;  // inverse-swz source col

  // A reg-staging addressing: instr j -> row j*16+arow0, 16B f32 col ac4
  int arow0 = tid >> 4;                      // 0..15  (row&7 == arow0&7)
  int ac4 = tid & 15;
  int aswz = (((ac4 >> 1) ^ (arow0 & 7)) * 16) + (ac4 & 1) * 8;

  // fragment read bases: row R = (wr|wc)*64 + mi*16 + lr; chunk (kk*4+g)^(R&7)
  int axor = lr & 7;
  int a_k0 = (wr * 64 + lr) * 128 + ((g ^ axor) * 16);
  int a_k1 = (wr * 64 + lr) * 128 + (((4 + g) ^ axor) * 16);
  int b_k0 = (wc * 64 + lr) * 128 + ((g ^ axor) * 16);
  int b_k1 = (wc * 64 + lr) * 128 + (((4 + g) ^ axor) * 16);

  f32x4 acc[4][4] = {};
  bf16x8 af[4], bfr[4];
  float4 aL[8];

  // prologue: stage B(0) into buf0, issue A(0). Queue = [B(0):4, A(0):8].
  STAGE_B(0, 0);
  ISSUE_A(0);

#pragma unroll 1
  for (int tt = 0; tt < 16; tt += 2) {
    TILE(tt, 0, 1);
    TILE(tt + 1, 1, 0);
  }

  // fused epilogue: max over 32 consecutive A-rows per n, + pkb
#pragma unroll
  for (int a = 0; a < 2; ++a) {
    int n = brow * 4 + wr * 2 + a;
#pragma unroll
    for (int ni = 0; ni < 4; ++ni) {
      float v = -3.402823466e38f;
#pragma unroll
      for (int mi = 2 * a; mi < 2 * a + 2; ++mi)
#pragma unroll
        for (int r = 0; r < 4; ++r) v = fmaxf(v, acc[mi][ni][r]);
      v = fmaxf(v, __shfl_xor(v, 16));
      v = fmaxf(v, __shfl_xor(v, 32));
      if (l < 16) {
        int col = bcol * 128 + wc * 64 + ni * 16 + l;
        out[(size_t)n * CC + col] = v + pkb[(size_t)n * CC + col];
      }
    }
  }
}

extern "C" void kernel_launch(void* const* d_in, const int* in_sizes, int n_in,
                              void* d_out, int out_size, void* d_ws, size_t ws_size,
                              hipStream_t stream) {
  const float* p = (const float*)d_in[0];   // (N, C, 1, 1)
  const float* o = (const float*)d_in[1];   // (N, M, C, 1, 1)
  const float* W = (const float*)d_in[5];   // (C, 2C)
  const float* b = (const float*)d_in[6];   // (C,)
  float* out = (float*)d_out;               // (N, C, 1, 1)

  char* ws = (char*)d_ws;
  unsigned short* p_bf  = (unsigned short*)ws;                 // 4 MB
  unsigned short* wp_bf = (unsigned short*)(ws + 4194304);     // 2 MB
  unsigned short* wo_bf = (unsigned short*)(ws + 6291456);     // 2 MB
  float*          pkb   = (float*)(ws + 8388608);              // 8 MB

  conv_pw<<<512, 256, 0, stream>>>(p, W, p_bf, wp_bf, wo_bf);
  gemm_pk<<<128, 256, 0, stream>>>(p_bf, wp_bf, b, pkb);
  // main: 512 row tiles x 8 col tiles = 4096 blocks, 256 threads
  gemm_fused<<<4096, 256, 0, stream>>>(o, wo_bf, pkb, out);
}

// Round 15
// 342.667 us; speedup vs baseline: 1.1850x; 1.1850x over previous
//
#include <hip/hip_runtime.h>
#include <hip/hip_bf16.h>

// out[n,d] = b[d] + pk[n,d] + max_m ok[n,m,d]
//   pk = p @ Wp^T  (2048x1024,  K=1024)   -- small 128-tile kernel
//   ok = o @ Wo^T  (65536x1024, K=1024)   -- fused-convert 128^2 GEMM
// R15 = R13 with B moved OUT of LDS: each wave reads its B fragments
// directly global->reg (line-coalesced: 4 g-groups tile one 64B line per
// row; B = 2MB, L2-resident per XCD). LDS = A only (16KB). Halves LDS
// issue traffic and removes the B-DMA drain that capped R13 at 29% MfmaUtil.
// A staging unchanged from R13 (proven): coalesced f32 reg-stage -> cvt ->
// XOR-swizzled ds_write_b64, single buffer, drain-per-tile.

#define NN 2048
#define MM 32
#define CC 1024

typedef __attribute__((ext_vector_type(8))) __bf16 bf16x8;
typedef __attribute__((ext_vector_type(4))) float f32x4;
typedef __attribute__((ext_vector_type(8))) unsigned short u16x8;
typedef __attribute__((ext_vector_type(4))) unsigned short u16x4;

__device__ inline unsigned short f2bf(float f) {
  union { __hip_bfloat16 h; unsigned short u; } v;
  v.h = __float2bfloat16(f);
  return v.u;
}

__device__ inline void gload_lds16(const void* g, void* l) {
  __builtin_amdgcn_global_load_lds(
      (const __attribute__((address_space(1))) void*)g,
      (__attribute__((address_space(3))) void*)l, 16, 0, 0);
}

// ---- convert person_features + split W into Wp/Wo (bf16) ----
__global__ void conv_pw(const float* __restrict__ p, const float* __restrict__ W,
                        unsigned short* __restrict__ pd,
                        unsigned short* __restrict__ wp,
                        unsigned short* __restrict__ wo) {
  const int PG = (NN * CC) / 8;
  const int WG = (CC * 2 * CC) / 8;
  int i = blockIdx.x * blockDim.x + threadIdx.x;
  int stride = gridDim.x * blockDim.x;
  for (; i < PG + WG; i += stride) {
    if (i < PG) {
      const float4* s = reinterpret_cast<const float4*>(p) + (size_t)i * 2;
      float4 a = s[0], b = s[1];
      u16x8 r;
      r[0] = f2bf(a.x); r[1] = f2bf(a.y); r[2] = f2bf(a.z); r[3] = f2bf(a.w);
      r[4] = f2bf(b.x); r[5] = f2bf(b.y); r[6] = f2bf(b.z); r[7] = f2bf(b.w);
      *reinterpret_cast<u16x8*>(pd + (size_t)i * 8) = r;
    } else {
      int f = i - PG;
      int e = f * 8;
      int d = e >> 11;
      int cc = e & 2047;
      const float4* s = reinterpret_cast<const float4*>(W) + (size_t)f * 2;
      float4 a = s[0], b = s[1];
      u16x8 r;
      r[0] = f2bf(a.x); r[1] = f2bf(a.y); r[2] = f2bf(a.z); r[3] = f2bf(a.w);
      r[4] = f2bf(b.x); r[5] = f2bf(b.y); r[6] = f2bf(b.z); r[7] = f2bf(b.w);
      unsigned short* o = (cc < CC) ? (wp + (size_t)d * CC + cc)
                                    : (wo + (size_t)d * CC + (cc - CC));
      *reinterpret_cast<u16x8*>(o) = r;
    }
  }
}

// ---- small 128x128 GEMM for pk+b ----
__global__ void gemm_pk(const unsigned short* __restrict__ A,
                        const unsigned short* __restrict__ B,
                        const float* __restrict__ bvec,
                        float* __restrict__ out) {
  __shared__ unsigned short As[128 * 64];
  __shared__ unsigned short Bs[128 * 64];

  int nb = gridDim.x;
  int chunk = nb >> 3;
  int obid = blockIdx.x;
  int vb = (obid & 7) * chunk + (obid >> 3);
  int bcol = vb & 7;
  int brow = vb >> 3;

  int tid = threadIdx.x;
  int l = tid & 63;
  int wid = tid >> 6;
  int wr = wid >> 1, wc = wid & 1;
  int lr = l & 15;
  int lk = (l >> 4) << 3;

  const unsigned short* gA = A + (size_t)brow * 128 * CC;
  const unsigned short* gB = B + (size_t)bcol * 128 * CC;

  f32x4 acc[4][4] = {};

  for (int kt = 0; kt < 16; ++kt) {
    int k0 = kt * 64;
#pragma unroll
    for (int j = 0; j < 4; ++j) {
      int f = (j * 256 + tid) * 8;
      int r = f >> 6;
      int c = f & 63;
      gload_lds16(gA + (size_t)r * CC + k0 + c, &As[f]);
      gload_lds16(gB + (size_t)r * CC + k0 + c, &Bs[f]);
    }
    __syncthreads();
#pragma unroll
    for (int kk = 0; kk < 2; ++kk) {
      bf16x8 af[4], bfr[4];
#pragma unroll
      for (int mi = 0; mi < 4; ++mi)
        af[mi] = *reinterpret_cast<const bf16x8*>(
            &As[(wr * 64 + mi * 16 + lr) * 64 + kk * 32 + lk]);
#pragma unroll
      for (int ni = 0; ni < 4; ++ni)
        bfr[ni] = *reinterpret_cast<const bf16x8*>(
            &Bs[(wc * 64 + ni * 16 + lr) * 64 + kk * 32 + lk]);
#pragma unroll
      for (int mi = 0; mi < 4; ++mi)
#pragma unroll
        for (int ni = 0; ni < 4; ++ni)
          acc[mi][ni] = __builtin_amdgcn_mfma_f32_16x16x32_bf16(
              af[mi], bfr[ni], acc[mi][ni], 0, 0, 0);
    }
    __syncthreads();
  }

#pragma unroll
  for (int mi = 0; mi < 4; ++mi) {
    int row = brow * 128 + wr * 64 + mi * 16 + (l >> 4) * 4;
#pragma unroll
    for (int ni = 0; ni < 4; ++ni) {
      int col = bcol * 128 + wc * 64 + ni * 16 + lr;
      float bb = bvec[col];
#pragma unroll
      for (int r = 0; r < 4; ++r)
        out[(size_t)(row + r) * CC + col] = acc[mi][ni][r] + bb;
    }
  }
}

// ==================== 128x128 fused GEMM, A-LDS only (R15) ==================
// LDS: A [128 rows x 64 bf16 = 128B rows] = 16KB, single buffer.
// Swizzle: LDS cell (row, chunk16B c) holds logical chunk c ^ (row&7).
// B read global->reg per wave: frag (ni,kk) = 16B/lane; lanes of a wave
// cover rows lr (16) x bytes g*16..+16 -> full 64B line per row.

#define BARRIER                                      \
  do {                                               \
    asm volatile("" ::: "memory");                   \
    __builtin_amdgcn_s_barrier();                    \
    asm volatile("" ::: "memory");                   \
  } while (0)

#define LGKM0 asm volatile("s_waitcnt lgkmcnt(0)" ::: "memory")

// A issue: instr j -> rows j*16 + (tid>>4), 16B col tid&15 (coalesced).
#define ISSUE_A(k0)                                                           \
  do {                                                                        \
    _Pragma("unroll") for (int j = 0; j < 8; ++j)                             \
        aL[j] = *reinterpret_cast<const float4*>(                             \
            gAf + (size_t)(j * 16 + arow0) * CC + (k0) + ac4 * 4);            \
  } while (0)

// cvt + swizzled ds_write_b64 into the A region
#define CVT_WRITE_A                                                           \
  do {                                                                        \
    _Pragma("unroll") for (int j = 0; j < 8; ++j) {                           \
      u16x4 r;                                                                \
      r[0] = f2bf(aL[j].x); r[1] = f2bf(aL[j].y);                             \
      r[2] = f2bf(aL[j].z); r[3] = f2bf(aL[j].w);                             \
      *reinterpret_cast<u16x4*>(lds + (j * 16 + arow0) * 128 + aswz) = r;     \
    }                                                                         \
  } while (0)

// B global->reg: 4 frags (16B each) for one kk of K-tile t
#define BLOAD(BF, t, kk)                                                      \
  do {                                                                        \
    _Pragma("unroll") for (int ni = 0; ni < 4; ++ni)                          \
        BF[ni] = *reinterpret_cast<const bf16x8*>(                            \
            gBw + (size_t)ni * 16 * CC + (t) * 64 + (kk) * 32 + g * 8);       \
  } while (0)

#define MFMA16X(BF)                                                           \
  do {                                                                        \
    __builtin_amdgcn_s_setprio(1);                                            \
    _Pragma("unroll") for (int mi = 0; mi < 4; ++mi)                          \
        _Pragma("unroll") for (int ni = 0; ni < 4; ++ni)                      \
            acc[mi][ni] = __builtin_amdgcn_mfma_f32_16x16x32_bf16(            \
                af[mi], BF[ni], acc[mi][ni], 0, 0, 0);                        \
    __builtin_amdgcn_s_setprio(0);                                            \
  } while (0)

__global__ __launch_bounds__(256, 3) void gemm_fused(
    const float* __restrict__ A,
    const unsigned short* __restrict__ B,
    const float* __restrict__ pkb,
    float* __restrict__ out) {
  __shared__ char lds[16384];

  int obid = blockIdx.x;                    // 4096 blocks
  int vb = (obid & 7) * 512 + (obid >> 3);  // XCD-contiguous (4096 % 8 == 0)
  int bcol = vb & 7;                        // 8 col tiles (col-fastest: L2 A-reuse)
  int brow = vb >> 3;                       // 512 row tiles

  int tid = threadIdx.x;
  int l = tid & 63;
  int wid = tid >> 6;
  int wr = wid >> 1;   // 0..1 (M half)
  int wc = wid & 1;    // 0..1 (N half)
  int lr = l & 15;
  int g = l >> 4;      // 0..3

  const float* gAf = A + (size_t)brow * 128 * CC;
  // per-lane B row base: row = bcol*128 + wc*64 + ni*16 + lr
  const unsigned short* gBw = B + (size_t)(bcol * 128 + wc * 64 + lr) * CC;

  // A reg-staging addressing: instr j -> row j*16+arow0, 16B f32 col ac4
  int arow0 = tid >> 4;                      // 0..15  (row&7 == arow0&7)
  int ac4 = tid & 15;
  int aswz = (((ac4 >> 1) ^ (arow0 & 7)) * 16) + (ac4 & 1) * 8;

  // A fragment read bases: row R = wr*64 + mi*16 + lr; chunk (kk*4+g)^(R&7)
  int axor = lr & 7;
  int a_k0 = (wr * 64 + lr) * 128 + ((g ^ axor) * 16);
  int a_k1 = (wr * 64 + lr) * 128 + (((4 + g) ^ axor) * 16);

  f32x4 acc[4][4] = {};
  bf16x8 af[4];
  bf16x8 bfrA[4], bfrB[4];
  float4 aL[8];

  // prologue: issue A(0).
  ISSUE_A(0);

#pragma unroll 1
  for (int t = 0; t < 16; ++t) {
    BARRIER;                 // all waves done reading A tile t-1
    CVT_WRITE_A;             // (compiler waits A(t) vmcnt) f32->bf16->LDS
    BLOAD(bfrA, t, 0);       // B(t) kk0 -> regs (L2)
    BLOAD(bfrB, t, 1);       // B(t) kk1 -> regs (L2)
    if (t + 1 < 16) ISSUE_A((t + 1) * 64);
    LGKM0;                   // our ds_writes drained
    BARRIER;                 // A tile t visible to all waves
    // kk0
#pragma unroll
    for (int mi = 0; mi < 4; ++mi)
      af[mi] = *(const bf16x8*)(lds + a_k0 + mi * 2048);
    LGKM0;
    MFMA16X(bfrA);
    // kk1
#pragma unroll
    for (int mi = 0; mi < 4; ++mi)
      af[mi] = *(const bf16x8*)(lds + a_k1 + mi * 2048);
    LGKM0;
    MFMA16X(bfrB);
  }

  // fused epilogue: max over 32 consecutive A-rows per n, + pkb
#pragma unroll
  for (int a = 0; a < 2; ++a) {
    int n = brow * 4 + wr * 2 + a;
#pragma unroll
    for (int ni = 0; ni < 4; ++ni) {
      float v = -3.402823466e38f;
#pragma unroll
      for (int mi = 2 * a; mi < 2 * a + 2; ++mi)
#pragma unroll
        for (int r = 0; r < 4; ++r) v = fmaxf(v, acc[mi][ni][r]);
      v = fmaxf(v, __shfl_xor(v, 16));
      v = fmaxf(v, __shfl_xor(v, 32));
      if (l < 16) {
        int col = bcol * 128 + wc * 64 + ni * 16 + l;
        out[(size_t)n * CC + col] = v + pkb[(size_t)n * CC + col];
      }
    }
  }
}

extern "C" void kernel_launch(void* const* d_in, const int* in_sizes, int n_in,
                              void* d_out, int out_size, void* d_ws, size_t ws_size,
                              hipStream_t stream) {
  const float* p = (const float*)d_in[0];   // (N, C, 1, 1)
  const float* o = (const float*)d_in[1];   // (N, M, C, 1, 1)
  const float* W = (const float*)d_in[5];   // (C, 2C)
  const float* b = (const float*)d_in[6];   // (C,)
  float* out = (float*)d_out;               // (N, C, 1, 1)

  char* ws = (char*)d_ws;
  unsigned short* p_bf  = (unsigned short*)ws;                 // 4 MB
  unsigned short* wp_bf = (unsigned short*)(ws + 4194304);     // 2 MB
  unsigned short* wo_bf = (unsigned short*)(ws + 6291456);     // 2 MB
  float*          pkb   = (float*)(ws + 8388608);              // 8 MB

  conv_pw<<<512, 256, 0, stream>>>(p, W, p_bf, wp_bf, wo_bf);
  gemm_pk<<<128, 256, 0, stream>>>(p_bf, wp_bf, b, pkb);
  // main: 512 row tiles x 8 col tiles = 4096 blocks, 256 threads
  gemm_fused<<<4096, 256, 0, stream>>>(o, wo_bf, pkb, out);
}

// Round 16
// 204.920 us; speedup vs baseline: 1.9816x; 1.6722x over previous
//
#include <hip/hip_runtime.h>
#include <hip/hip_bf16.h>

// out[n,d] = b[d] + pk[n,d] + max_m ok[n,m,d]
//   pk = p @ Wp^T  (2048x1024,  K=1024)   -- small 128-tile kernel
//   ok = o @ Wo^T  (65536x1024, K=1024)   -- fused-convert 128^2 GEMM
// R16 = R13 with the B-DMA hoisted to the top of the staging region:
// after barrier-1 the single B buffer's readers (tile t-1) are done, so
// STAGE_B(t) issues FIRST; the cvt+issue phase (~200+ cy) then covers the
// DMA's L2 latency before VMCNT(8) waits on it (R13 waited ~10 instrs in).
// Ledger: enter=[A(t):8]; +B:4; VMCNT(4) retires A(t); cvt+write; +A(t+1):8;
// VMCNT(8) retires B(t); t=15: VMCNT(0). Everything else identical to R13.

#define NN 2048
#define MM 32
#define CC 1024

typedef __attribute__((ext_vector_type(8))) __bf16 bf16x8;
typedef __attribute__((ext_vector_type(4))) float f32x4;
typedef __attribute__((ext_vector_type(8))) unsigned short u16x8;
typedef __attribute__((ext_vector_type(4))) unsigned short u16x4;

__device__ inline unsigned short f2bf(float f) {
  union { __hip_bfloat16 h; unsigned short u; } v;
  v.h = __float2bfloat16(f);
  return v.u;
}

__device__ inline void gload_lds16(const void* g, void* l) {
  __builtin_amdgcn_global_load_lds(
      (const __attribute__((address_space(1))) void*)g,
      (__attribute__((address_space(3))) void*)l, 16, 0, 0);
}

// ---- convert person_features + split W into Wp/Wo (bf16) ----
__global__ void conv_pw(const float* __restrict__ p, const float* __restrict__ W,
                        unsigned short* __restrict__ pd,
                        unsigned short* __restrict__ wp,
                        unsigned short* __restrict__ wo) {
  const int PG = (NN * CC) / 8;
  const int WG = (CC * 2 * CC) / 8;
  int i = blockIdx.x * blockDim.x + threadIdx.x;
  int stride = gridDim.x * blockDim.x;
  for (; i < PG + WG; i += stride) {
    if (i < PG) {
      const float4* s = reinterpret_cast<const float4*>(p) + (size_t)i * 2;
      float4 a = s[0], b = s[1];
      u16x8 r;
      r[0] = f2bf(a.x); r[1] = f2bf(a.y); r[2] = f2bf(a.z); r[3] = f2bf(a.w);
      r[4] = f2bf(b.x); r[5] = f2bf(b.y); r[6] = f2bf(b.z); r[7] = f2bf(b.w);
      *reinterpret_cast<u16x8*>(pd + (size_t)i * 8) = r;
    } else {
      int f = i - PG;
      int e = f * 8;
      int d = e >> 11;
      int cc = e & 2047;
      const float4* s = reinterpret_cast<const float4*>(W) + (size_t)f * 2;
      float4 a = s[0], b = s[1];
      u16x8 r;
      r[0] = f2bf(a.x); r[1] = f2bf(a.y); r[2] = f2bf(a.z); r[3] = f2bf(a.w);
      r[4] = f2bf(b.x); r[5] = f2bf(b.y); r[6] = f2bf(b.z); r[7] = f2bf(b.w);
      unsigned short* o = (cc < CC) ? (wp + (size_t)d * CC + cc)
                                    : (wo + (size_t)d * CC + (cc - CC));
      *reinterpret_cast<u16x8*>(o) = r;
    }
  }
}

// ---- small 128x128 GEMM for pk+b ----
__global__ void gemm_pk(const unsigned short* __restrict__ A,
                        const unsigned short* __restrict__ B,
                        const float* __restrict__ bvec,
                        float* __restrict__ out) {
  __shared__ unsigned short As[128 * 64];
  __shared__ unsigned short Bs[128 * 64];

  int nb = gridDim.x;
  int chunk = nb >> 3;
  int obid = blockIdx.x;
  int vb = (obid & 7) * chunk + (obid >> 3);
  int bcol = vb & 7;
  int brow = vb >> 3;

  int tid = threadIdx.x;
  int l = tid & 63;
  int wid = tid >> 6;
  int wr = wid >> 1, wc = wid & 1;
  int lr = l & 15;
  int lk = (l >> 4) << 3;

  const unsigned short* gA = A + (size_t)brow * 128 * CC;
  const unsigned short* gB = B + (size_t)bcol * 128 * CC;

  f32x4 acc[4][4] = {};

  for (int kt = 0; kt < 16; ++kt) {
    int k0 = kt * 64;
#pragma unroll
    for (int j = 0; j < 4; ++j) {
      int f = (j * 256 + tid) * 8;
      int r = f >> 6;
      int c = f & 63;
      gload_lds16(gA + (size_t)r * CC + k0 + c, &As[f]);
      gload_lds16(gB + (size_t)r * CC + k0 + c, &Bs[f]);
    }
    __syncthreads();
#pragma unroll
    for (int kk = 0; kk < 2; ++kk) {
      bf16x8 af[4], bfr[4];
#pragma unroll
      for (int mi = 0; mi < 4; ++mi)
        af[mi] = *reinterpret_cast<const bf16x8*>(
            &As[(wr * 64 + mi * 16 + lr) * 64 + kk * 32 + lk]);
#pragma unroll
      for (int ni = 0; ni < 4; ++ni)
        bfr[ni] = *reinterpret_cast<const bf16x8*>(
            &Bs[(wc * 64 + ni * 16 + lr) * 64 + kk * 32 + lk]);
#pragma unroll
      for (int mi = 0; mi < 4; ++mi)
#pragma unroll
        for (int ni = 0; ni < 4; ++ni)
          acc[mi][ni] = __builtin_amdgcn_mfma_f32_16x16x32_bf16(
              af[mi], bfr[ni], acc[mi][ni], 0, 0, 0);
    }
    __syncthreads();
  }

#pragma unroll
  for (int mi = 0; mi < 4; ++mi) {
    int row = brow * 128 + wr * 64 + mi * 16 + (l >> 4) * 4;
#pragma unroll
    for (int ni = 0; ni < 4; ++ni) {
      int col = bcol * 128 + wc * 64 + ni * 16 + lr;
      float bb = bvec[col];
#pragma unroll
      for (int r = 0; r < 4; ++r)
        out[(size_t)(row + r) * CC + col] = acc[mi][ni][r] + bb;
    }
  }
}

// ==================== 128x128 single-buffer fused GEMM (R16) ================
// LDS: A [128 rows x 64 bf16 = 128B rows] @ 0 (16KB); B same @ 16384. 32KB.
// Swizzle: LDS cell (row, chunk16B c) holds logical chunk c ^ (row&7).

#define BARRIER                                      \
  do {                                               \
    asm volatile("" ::: "memory");                   \
    __builtin_amdgcn_s_barrier();                    \
    asm volatile("" ::: "memory");                   \
  } while (0)

#define LGKM0 asm volatile("s_waitcnt lgkmcnt(0)" ::: "memory")
#define VMCNT(n) asm volatile("s_waitcnt vmcnt(" #n ")" ::: "memory")

// B stage: 128x64 bf16 = 16KB; 4 x gload_lds16/thread, inverse-swz source.
#define STAGE_B(k0)                                                           \
  do {                                                                        \
    _Pragma("unroll") for (int j = 0; j < 4; ++j)                             \
        gload_lds16(gB + (size_t)(j * 32 + brr) * CC + (k0) + bsc,            \
                    lds + 16384 + (j * 256 + tid) * 16);                      \
  } while (0)

// A issue: instr j -> rows j*16 + (tid>>4), 16B col tid&15 (coalesced).
#define ISSUE_A(k0)                                                           \
  do {                                                                        \
    _Pragma("unroll") for (int j = 0; j < 8; ++j)                             \
        aL[j] = *reinterpret_cast<const float4*>(                             \
            gAf + (size_t)(j * 16 + arow0) * CC + (k0) + ac4 * 4);            \
  } while (0)

// cvt + swizzled ds_write_b64 into the A region
#define CVT_WRITE_A                                                           \
  do {                                                                        \
    _Pragma("unroll") for (int j = 0; j < 8; ++j) {                           \
      u16x4 r;                                                                \
      r[0] = f2bf(aL[j].x); r[1] = f2bf(aL[j].y);                             \
      r[2] = f2bf(aL[j].z); r[3] = f2bf(aL[j].w);                             \
      *reinterpret_cast<u16x4*>(lds + (j * 16 + arow0) * 128 + aswz) = r;     \
    }                                                                         \
  } while (0)

#define MFMA16X                                                               \
  do {                                                                        \
    __builtin_amdgcn_s_setprio(1);                                            \
    _Pragma("unroll") for (int mi = 0; mi < 4; ++mi)                          \
        _Pragma("unroll") for (int ni = 0; ni < 4; ++ni)                      \
            acc[mi][ni] = __builtin_amdgcn_mfma_f32_16x16x32_bf16(            \
                af[mi], bfr[ni], acc[mi][ni], 0, 0, 0);                       \
    __builtin_amdgcn_s_setprio(0);                                            \
  } while (0)

__global__ __launch_bounds__(256, 3) void gemm_fused(
    const float* __restrict__ A,
    const unsigned short* __restrict__ B,
    const float* __restrict__ pkb,
    float* __restrict__ out) {
  __shared__ char lds[32768];

  int obid = blockIdx.x;                    // 4096 blocks
  int vb = (obid & 7) * 512 + (obid >> 3);  // XCD-contiguous (4096 % 8 == 0)
  int bcol = vb & 7;                        // 8 col tiles (col-fastest: L2 A-reuse)
  int brow = vb >> 3;                       // 512 row tiles

  int tid = threadIdx.x;
  int l = tid & 63;
  int wid = tid >> 6;
  int wr = wid >> 1;   // 0..1 (M half)
  int wc = wid & 1;    // 0..1 (N half)
  int lr = l & 15;
  int g = l >> 4;      // 0..3

  const float* gAf = A + (size_t)brow * 128 * CC;
  const unsigned short* gB = B + (size_t)bcol * 128 * CC;

  // B staging addressing
  int brr = tid >> 3;                            // 0..31
  int bsc = ((tid & 7) ^ ((tid >> 3) & 7)) * 8;  // inverse-swz source col

  // A reg-staging addressing: instr j -> row j*16+arow0, 16B f32 col ac4
  int arow0 = tid >> 4;                      // 0..15  (row&7 == arow0&7)
  int ac4 = tid & 15;                        // 16 chunks of 16B per 256B row
  int aswz = (((ac4 >> 1) ^ (arow0 & 7)) * 16) + (ac4 & 1) * 8;

  // fragment read bases: row R = (wr|wc)*64 + mi*16 + lr; chunk (kk*4+g)^(R&7)
  int axor = lr & 7;
  int a_k0 = (wr * 64 + lr) * 128 + ((g ^ axor) * 16);
  int a_k1 = (wr * 64 + lr) * 128 + (((4 + g) ^ axor) * 16);
  int b_k0 = 16384 + (wc * 64 + lr) * 128 + ((g ^ axor) * 16);
  int b_k1 = 16384 + (wc * 64 + lr) * 128 + (((4 + g) ^ axor) * 16);

  f32x4 acc[4][4] = {};
  bf16x8 af[4], bfr[4];
  float4 aL[8];

  // prologue: issue A(0); loop handles the rest.
  ISSUE_A(0);

#pragma unroll 1
  for (int t = 0; t < 16; ++t) {
    BARRIER;                 // all waves done reading tile t-1's LDS (A and B)
    STAGE_B(t * 64);         // B(t) DMA [4] -- issued EARLY for latency cover
    VMCNT(4);                // retire A(t) regs (8, older); B's 4 stay
    CVT_WRITE_A;             // A(t) f32 regs -> bf16 LDS (swizzled)
    if (t + 1 < 16) ISSUE_A((t + 1) * 64);  // [8 vmem, younger than B]
    LGKM0;                   // our ds_writes visible
    if (t + 1 < 16) { VMCNT(8); } else { VMCNT(0); }  // retire B(t) DMA
    BARRIER;                 // LDS tile t ready for all waves
    // compute kk=0
#pragma unroll
    for (int mi = 0; mi < 4; ++mi)
      af[mi] = *(const bf16x8*)(lds + a_k0 + mi * 2048);
#pragma unroll
    for (int ni = 0; ni < 4; ++ni)
      bfr[ni] = *(const bf16x8*)(lds + b_k0 + ni * 2048);
    LGKM0;
    MFMA16X;
    // compute kk=1
#pragma unroll
    for (int mi = 0; mi < 4; ++mi)
      af[mi] = *(const bf16x8*)(lds + a_k1 + mi * 2048);
#pragma unroll
    for (int ni = 0; ni < 4; ++ni)
      bfr[ni] = *(const bf16x8*)(lds + b_k1 + ni * 2048);
    LGKM0;
    MFMA16X;
  }

  // fused epilogue: max over 32 consecutive A-rows per n, + pkb
#pragma unroll
  for (int a = 0; a < 2; ++a) {
    int n = brow * 4 + wr * 2 + a;
#pragma unroll
    for (int ni = 0; ni < 4; ++ni) {
      float v = -3.402823466e38f;
#pragma unroll
      for (int mi = 2 * a; mi < 2 * a + 2; ++mi)
#pragma unroll
        for (int r = 0; r < 4; ++r) v = fmaxf(v, acc[mi][ni][r]);
      v = fmaxf(v, __shfl_xor(v, 16));
      v = fmaxf(v, __shfl_xor(v, 32));
      if (l < 16) {
        int col = bcol * 128 + wc * 64 + ni * 16 + l;
        out[(size_t)n * CC + col] = v + pkb[(size_t)n * CC + col];
      }
    }
  }
}

extern "C" void kernel_launch(void* const* d_in, const int* in_sizes, int n_in,
                              void* d_out, int out_size, void* d_ws, size_t ws_size,
                              hipStream_t stream) {
  const float* p = (const float*)d_in[0];   // (N, C, 1, 1)
  const float* o = (const float*)d_in[1];   // (N, M, C, 1, 1)
  const float* W = (const float*)d_in[5];   // (C, 2C)
  const float* b = (const float*)d_in[6];   // (C,)
  float* out = (float*)d_out;               // (N, C, 1, 1)

  char* ws = (char*)d_ws;
  unsigned short* p_bf  = (unsigned short*)ws;                 // 4 MB
  unsigned short* wp_bf = (unsigned short*)(ws + 4194304);     // 2 MB
  unsigned short* wo_bf = (unsigned short*)(ws + 6291456);     // 2 MB
  float*          pkb   = (float*)(ws + 8388608);              // 8 MB

  conv_pw<<<512, 256, 0, stream>>>(p, W, p_bf, wp_bf, wo_bf);
  gemm_pk<<<128, 256, 0, stream>>>(p_bf, wp_bf, b, pkb);
  // main: 512 row tiles x 8 col tiles = 4096 blocks, 256 threads
  gemm_fused<<<4096, 256, 0, stream>>>(o, wo_bf, pkb, out);
}

// Round 17
// 195.584 us; speedup vs baseline: 2.0762x; 1.0477x over previous
//
#include <hip/hip_runtime.h>
#include <hip/hip_bf16.h>

// out[n,d] = b[d] + pk[n,d] + max_m ok[n,m,d]
//   pk = p @ Wp^T  (2048x1024,  K=1024)   -- small 128-tile kernel
//   ok = o @ Wo^T  (65536x1024, K=1024)   -- fused-convert 128^2 GEMM
// R17 = R13 (exact staging order; R16's B-hoist reverted) + kk-pipelined
// fragment reads: af(kk0)+bfr(kk0)+af2(kk1) issued together, lgkmcnt(4)
// -> MFMA kk0 (af2 reads fly under it), bfr(kk1) reuses bfr, lgkmcnt(0)
// -> MFMA kk1. Removes one serial LDS-latency stall per tile (+16 VGPR).

#define NN 2048
#define MM 32
#define CC 1024

typedef __attribute__((ext_vector_type(8))) __bf16 bf16x8;
typedef __attribute__((ext_vector_type(4))) float f32x4;
typedef __attribute__((ext_vector_type(8))) unsigned short u16x8;
typedef __attribute__((ext_vector_type(4))) unsigned short u16x4;

__device__ inline unsigned short f2bf(float f) {
  union { __hip_bfloat16 h; unsigned short u; } v;
  v.h = __float2bfloat16(f);
  return v.u;
}

__device__ inline void gload_lds16(const void* g, void* l) {
  __builtin_amdgcn_global_load_lds(
      (const __attribute__((address_space(1))) void*)g,
      (__attribute__((address_space(3))) void*)l, 16, 0, 0);
}

// ---- convert person_features + split W into Wp/Wo (bf16) ----
__global__ void conv_pw(const float* __restrict__ p, const float* __restrict__ W,
                        unsigned short* __restrict__ pd,
                        unsigned short* __restrict__ wp,
                        unsigned short* __restrict__ wo) {
  const int PG = (NN * CC) / 8;
  const int WG = (CC * 2 * CC) / 8;
  int i = blockIdx.x * blockDim.x + threadIdx.x;
  int stride = gridDim.x * blockDim.x;
  for (; i < PG + WG; i += stride) {
    if (i < PG) {
      const float4* s = reinterpret_cast<const float4*>(p) + (size_t)i * 2;
      float4 a = s[0], b = s[1];
      u16x8 r;
      r[0] = f2bf(a.x); r[1] = f2bf(a.y); r[2] = f2bf(a.z); r[3] = f2bf(a.w);
      r[4] = f2bf(b.x); r[5] = f2bf(b.y); r[6] = f2bf(b.z); r[7] = f2bf(b.w);
      *reinterpret_cast<u16x8*>(pd + (size_t)i * 8) = r;
    } else {
      int f = i - PG;
      int e = f * 8;
      int d = e >> 11;
      int cc = e & 2047;
      const float4* s = reinterpret_cast<const float4*>(W) + (size_t)f * 2;
      float4 a = s[0], b = s[1];
      u16x8 r;
      r[0] = f2bf(a.x); r[1] = f2bf(a.y); r[2] = f2bf(a.z); r[3] = f2bf(a.w);
      r[4] = f2bf(b.x); r[5] = f2bf(b.y); r[6] = f2bf(b.z); r[7] = f2bf(b.w);
      unsigned short* o = (cc < CC) ? (wp + (size_t)d * CC + cc)
                                    : (wo + (size_t)d * CC + (cc - CC));
      *reinterpret_cast<u16x8*>(o) = r;
    }
  }
}

// ---- small 128x128 GEMM for pk+b ----
__global__ void gemm_pk(const unsigned short* __restrict__ A,
                        const unsigned short* __restrict__ B,
                        const float* __restrict__ bvec,
                        float* __restrict__ out) {
  __shared__ unsigned short As[128 * 64];
  __shared__ unsigned short Bs[128 * 64];

  int nb = gridDim.x;
  int chunk = nb >> 3;
  int obid = blockIdx.x;
  int vb = (obid & 7) * chunk + (obid >> 3);
  int bcol = vb & 7;
  int brow = vb >> 3;

  int tid = threadIdx.x;
  int l = tid & 63;
  int wid = tid >> 6;
  int wr = wid >> 1, wc = wid & 1;
  int lr = l & 15;
  int lk = (l >> 4) << 3;

  const unsigned short* gA = A + (size_t)brow * 128 * CC;
  const unsigned short* gB = B + (size_t)bcol * 128 * CC;

  f32x4 acc[4][4] = {};

  for (int kt = 0; kt < 16; ++kt) {
    int k0 = kt * 64;
#pragma unroll
    for (int j = 0; j < 4; ++j) {
      int f = (j * 256 + tid) * 8;
      int r = f >> 6;
      int c = f & 63;
      gload_lds16(gA + (size_t)r * CC + k0 + c, &As[f]);
      gload_lds16(gB + (size_t)r * CC + k0 + c, &Bs[f]);
    }
    __syncthreads();
#pragma unroll
    for (int kk = 0; kk < 2; ++kk) {
      bf16x8 af[4], bfr[4];
#pragma unroll
      for (int mi = 0; mi < 4; ++mi)
        af[mi] = *reinterpret_cast<const bf16x8*>(
            &As[(wr * 64 + mi * 16 + lr) * 64 + kk * 32 + lk]);
#pragma unroll
      for (int ni = 0; ni < 4; ++ni)
        bfr[ni] = *reinterpret_cast<const bf16x8*>(
            &Bs[(wc * 64 + ni * 16 + lr) * 64 + kk * 32 + lk]);
#pragma unroll
      for (int mi = 0; mi < 4; ++mi)
#pragma unroll
        for (int ni = 0; ni < 4; ++ni)
          acc[mi][ni] = __builtin_amdgcn_mfma_f32_16x16x32_bf16(
              af[mi], bfr[ni], acc[mi][ni], 0, 0, 0);
    }
    __syncthreads();
  }

#pragma unroll
  for (int mi = 0; mi < 4; ++mi) {
    int row = brow * 128 + wr * 64 + mi * 16 + (l >> 4) * 4;
#pragma unroll
    for (int ni = 0; ni < 4; ++ni) {
      int col = bcol * 128 + wc * 64 + ni * 16 + lr;
      float bb = bvec[col];
#pragma unroll
      for (int r = 0; r < 4; ++r)
        out[(size_t)(row + r) * CC + col] = acc[mi][ni][r] + bb;
    }
  }
}

// ==================== 128x128 single-buffer fused GEMM (R17) ================
// LDS: A [128 rows x 64 bf16 = 128B rows] @ 0 (16KB); B same @ 16384. 32KB.
// Swizzle: LDS cell (row, chunk16B c) holds logical chunk c ^ (row&7).

#define BARRIER                                      \
  do {                                               \
    asm volatile("" ::: "memory");                   \
    __builtin_amdgcn_s_barrier();                    \
    asm volatile("" ::: "memory");                   \
  } while (0)

#define LGKM(n) asm volatile("s_waitcnt lgkmcnt(" #n ")" ::: "memory")
#define VMCNT(n) asm volatile("s_waitcnt vmcnt(" #n ")" ::: "memory")

// B stage: 128x64 bf16 = 16KB; 4 x gload_lds16/thread, inverse-swz source.
#define STAGE_B(k0)                                                           \
  do {                                                                        \
    _Pragma("unroll") for (int j = 0; j < 4; ++j)                             \
        gload_lds16(gB + (size_t)(j * 32 + brr) * CC + (k0) + bsc,            \
                    lds + 16384 + (j * 256 + tid) * 16);                      \
  } while (0)

// A issue: instr j -> rows j*16 + (tid>>4), 16B col tid&15 (coalesced).
#define ISSUE_A(k0)                                                           \
  do {                                                                        \
    _Pragma("unroll") for (int j = 0; j < 8; ++j)                             \
        aL[j] = *reinterpret_cast<const float4*>(                             \
            gAf + (size_t)(j * 16 + arow0) * CC + (k0) + ac4 * 4);            \
  } while (0)

// cvt + swizzled ds_write_b64 into the A region
#define CVT_WRITE_A                                                           \
  do {                                                                        \
    _Pragma("unroll") for (int j = 0; j < 8; ++j) {                           \
      u16x4 r;                                                                \
      r[0] = f2bf(aL[j].x); r[1] = f2bf(aL[j].y);                             \
      r[2] = f2bf(aL[j].z); r[3] = f2bf(aL[j].w);                             \
      *reinterpret_cast<u16x4*>(lds + (j * 16 + arow0) * 128 + aswz) = r;     \
    }                                                                         \
  } while (0)

#define MFMA16X(AF)                                                           \
  do {                                                                        \
    __builtin_amdgcn_s_setprio(1);                                            \
    _Pragma("unroll") for (int mi = 0; mi < 4; ++mi)                          \
        _Pragma("unroll") for (int ni = 0; ni < 4; ++ni)                      \
            acc[mi][ni] = __builtin_amdgcn_mfma_f32_16x16x32_bf16(            \
                AF[mi], bfr[ni], acc[mi][ni], 0, 0, 0);                       \
    __builtin_amdgcn_s_setprio(0);                                            \
  } while (0)

__global__ __launch_bounds__(256, 3) void gemm_fused(
    const float* __restrict__ A,
    const unsigned short* __restrict__ B,
    const float* __restrict__ pkb,
    float* __restrict__ out) {
  __shared__ char lds[32768];

  int obid = blockIdx.x;                    // 4096 blocks
  int vb = (obid & 7) * 512 + (obid >> 3);  // XCD-contiguous (4096 % 8 == 0)
  int bcol = vb & 7;                        // 8 col tiles (col-fastest: L2 A-reuse)
  int brow = vb >> 3;                       // 512 row tiles

  int tid = threadIdx.x;
  int l = tid & 63;
  int wid = tid >> 6;
  int wr = wid >> 1;   // 0..1 (M half)
  int wc = wid & 1;    // 0..1 (N half)
  int lr = l & 15;
  int g = l >> 4;      // 0..3

  const float* gAf = A + (size_t)brow * 128 * CC;
  const unsigned short* gB = B + (size_t)bcol * 128 * CC;

  // B staging addressing
  int brr = tid >> 3;                            // 0..31
  int bsc = ((tid & 7) ^ ((tid >> 3) & 7)) * 8;  // inverse-swz source col

  // A reg-staging addressing: instr j -> row j*16+arow0, 16B f32 col ac4
  int arow0 = tid >> 4;                      // 0..15  (row&7 == arow0&7)
  int ac4 = tid & 15;                        // 16 chunks of 16B per 256B row
  int aswz = (((ac4 >> 1) ^ (arow0 & 7)) * 16) + (ac4 & 1) * 8;

  // fragment read bases: row R = (wr|wc)*64 + mi*16 + lr; chunk (kk*4+g)^(R&7)
  int axor = lr & 7;
  int a_k0 = (wr * 64 + lr) * 128 + ((g ^ axor) * 16);
  int a_k1 = (wr * 64 + lr) * 128 + (((4 + g) ^ axor) * 16);
  int b_k0 = 16384 + (wc * 64 + lr) * 128 + ((g ^ axor) * 16);
  int b_k1 = 16384 + (wc * 64 + lr) * 128 + (((4 + g) ^ axor) * 16);

  f32x4 acc[4][4] = {};
  bf16x8 af[4], af2[4], bfr[4];
  float4 aL[8];

  // prologue: issue A(0); loop handles the rest.
  ISSUE_A(0);

#pragma unroll 1
  for (int t = 0; t < 16; ++t) {
    BARRIER;                 // all waves done reading tile t-1's LDS
    VMCNT(0);                // retire A(t) loads (issued one tile ago)
    CVT_WRITE_A;             // A(t) f32 regs -> bf16 LDS (swizzled)
    STAGE_B(t * 64);         // B(t) DMA  [4 vmem]
    if (t + 1 < 16) ISSUE_A((t + 1) * 64);  // [8 vmem, younger]
    LGKM(0);                 // our ds_writes visible
    if (t + 1 < 16) { VMCNT(8); } else { VMCNT(0); }  // retire B(t) DMA
    BARRIER;                 // LDS tile t ready for all waves
    // pipelined compute: issue kk0 frags + kk1 A frags together
#pragma unroll
    for (int mi = 0; mi < 4; ++mi)
      af[mi] = *(const bf16x8*)(lds + a_k0 + mi * 2048);
#pragma unroll
    for (int ni = 0; ni < 4; ++ni)
      bfr[ni] = *(const bf16x8*)(lds + b_k0 + ni * 2048);
#pragma unroll
    for (int mi = 0; mi < 4; ++mi)
      af2[mi] = *(const bf16x8*)(lds + a_k1 + mi * 2048);
    LGKM(4);                 // kk0's 8 reads done; af2's 4 still flying
    MFMA16X(af);             // kk0 (af2 reads complete underneath)
#pragma unroll
    for (int ni = 0; ni < 4; ++ni)
      bfr[ni] = *(const bf16x8*)(lds + b_k1 + ni * 2048);
    LGKM(0);                 // af2 + bfr(kk1) ready
    MFMA16X(af2);            // kk1
  }

  // fused epilogue: max over 32 consecutive A-rows per n, + pkb
#pragma unroll
  for (int a = 0; a < 2; ++a) {
    int n = brow * 4 + wr * 2 + a;
#pragma unroll
    for (int ni = 0; ni < 4; ++ni) {
      float v = -3.402823466e38f;
#pragma unroll
      for (int mi = 2 * a; mi < 2 * a + 2; ++mi)
#pragma unroll
        for (int r = 0; r < 4; ++r) v = fmaxf(v, acc[mi][ni][r]);
      v = fmaxf(v, __shfl_xor(v, 16));
      v = fmaxf(v, __shfl_xor(v, 32));
      if (l < 16) {
        int col = bcol * 128 + wc * 64 + ni * 16 + l;
        out[(size_t)n * CC + col] = v + pkb[(size_t)n * CC + col];
      }
    }
  }
}

extern "C" void kernel_launch(void* const* d_in, const int* in_sizes, int n_in,
                              void* d_out, int out_size, void* d_ws, size_t ws_size,
                              hipStream_t stream) {
  const float* p = (const float*)d_in[0];   // (N, C, 1, 1)
  const float* o = (const float*)d_in[1];   // (N, M, C, 1, 1)
  const float* W = (const float*)d_in[5];   // (C, 2C)
  const float* b = (const float*)d_in[6];   // (C,)
  float* out = (float*)d_out;               // (N, C, 1, 1)

  char* ws = (char*)d_ws;
  unsigned short* p_bf  = (unsigned short*)ws;                 // 4 MB
  unsigned short* wp_bf = (unsigned short*)(ws + 4194304);     // 2 MB
  unsigned short* wo_bf = (unsigned short*)(ws + 6291456);     // 2 MB
  float*          pkb   = (float*)(ws + 8388608);              // 8 MB

  conv_pw<<<512, 256, 0, stream>>>(p, W, p_bf, wp_bf, wo_bf);
  gemm_pk<<<128, 256, 0, stream>>>(p_bf, wp_bf, b, pkb);
  // main: 512 row tiles x 8 col tiles = 4096 blocks, 256 threads
  gemm_fused<<<4096, 256, 0, stream>>>(o, wo_bf, pkb, out);
}